// Round 1
// baseline (367.513 us; speedup 1.0000x reference)
//
#include <hip/hip_runtime.h>

// Segment mean pooling: out[s, :] = mean(x[pointer[s]:pointer[s+1], :])
// x: [524288, 128] f32, pointer: [1025] i32, out: [1024, 128] f32.
//
// Flat, load-balanced decomposition: every block sums exactly 512 contiguous
// rows; partial sums are scaled by 1/count and combined with HW fp32 atomics.
// This avoids the straggler tail of a block-per-segment design (random segment
// sizes, max ~3500 rows).

constexpr int kNodes        = 524288;
constexpr int kGraphs       = 1024;
constexpr int kFeat         = 128;
constexpr int kQuads        = kFeat / 4;   // 32 float4 per row
constexpr int kBlock        = 256;
constexpr int kRowsPerBlock = 512;         // kNodes / gridDim
constexpr int kRowsPerSlot  = 64;          // 8 half-wave slots per block

__global__ __launch_bounds__(kBlock) void seg_mean_kernel(
    const float* __restrict__ x,
    const int* __restrict__ pointer,
    float* __restrict__ out) {
  __shared__ int sp[kGraphs + 1];
  for (int i = threadIdx.x; i <= kGraphs; i += kBlock) sp[i] = pointer[i];
  __syncthreads();

  const int slot = threadIdx.x >> 5;   // 0..7
  const int q    = threadIdx.x & 31;   // float4 column within the row
  const int base = blockIdx.x * kRowsPerBlock + slot * kRowsPerSlot;
  const int rend = base + kRowsPerSlot;

  // seg = max i in [0, kGraphs-1] with sp[i] <= base  (searchsorted-right - 1;
  // handles duplicate pointer values / empty segments). Uniform per half-wave.
  int lo = 0, hi = kGraphs - 1;
  while (lo < hi) {
    int mid = (lo + hi + 1) >> 1;
    if (sp[mid] <= base) lo = mid; else hi = mid - 1;
  }
  int seg  = lo;
  int next = sp[seg + 1];

  const float4* __restrict__ xv = reinterpret_cast<const float4*>(x);
  float ax = 0.f, ay = 0.f, az = 0.f, aw = 0.f;

  int r = base;
  while (r < rend) {
    // Crossed one (or more, if empty segments) boundaries: flush and advance.
    while (r >= next) {
      const int   cnt = next - sp[seg];
      const float inv = 1.0f / (float)(cnt > 0 ? cnt : 1);
      float* o = out + (size_t)seg * kFeat + (q << 2);
      unsafeAtomicAdd(o + 0, ax * inv);
      unsafeAtomicAdd(o + 1, ay * inv);
      unsafeAtomicAdd(o + 2, az * inv);
      unsafeAtomicAdd(o + 3, aw * inv);
      ax = ay = az = aw = 0.f;
      ++seg;
      next = sp[seg + 1];
    }
    const int stop = next < rend ? next : rend;   // rows [r, stop) all in seg
    const float4* p = xv + (size_t)r * kQuads + q;
    // Fast path: 4 independent dwordx4 loads in flight (latency hiding).
    for (; r + 4 <= stop; r += 4, p += 4 * kQuads) {
      const float4 v0 = p[0 * kQuads];
      const float4 v1 = p[1 * kQuads];
      const float4 v2 = p[2 * kQuads];
      const float4 v3 = p[3 * kQuads];
      ax += v0.x; ay += v0.y; az += v0.z; aw += v0.w;
      ax += v1.x; ay += v1.y; az += v1.z; aw += v1.w;
      ax += v2.x; ay += v2.y; az += v2.z; aw += v2.w;
      ax += v3.x; ay += v3.y; az += v3.z; aw += v3.w;
    }
    for (; r < stop; ++r, p += kQuads) {
      const float4 v = p[0];
      ax += v.x; ay += v.y; az += v.z; aw += v.w;
    }
  }

  // Final flush for the segment containing the last row of this slot.
  {
    const int   cnt = next - sp[seg];
    const float inv = 1.0f / (float)(cnt > 0 ? cnt : 1);
    float* o = out + (size_t)seg * kFeat + (q << 2);
    unsafeAtomicAdd(o + 0, ax * inv);
    unsafeAtomicAdd(o + 1, ay * inv);
    unsafeAtomicAdd(o + 2, az * inv);
    unsafeAtomicAdd(o + 3, aw * inv);
  }
}

extern "C" void kernel_launch(void* const* d_in, const int* in_sizes, int n_in,
                              void* d_out, int out_size, void* d_ws, size_t ws_size,
                              hipStream_t stream) {
  const float* x       = (const float*)d_in[0];
  const int*   pointer = (const int*)d_in[1];
  float*       out     = (float*)d_out;

  // Harness poisons d_out with 0xAA before every launch; atomics need zeros.
  hipMemsetAsync(out, 0, (size_t)out_size * sizeof(float), stream);

  const int grid = kNodes / kRowsPerBlock;  // 1024 blocks, identical work each
  seg_mean_kernel<<<grid, kBlock, 0, stream>>>(x, pointer, out);
}